// Round 11
// baseline (405.621 us; speedup 1.0000x reference)
//
#include <hip/hip_runtime.h>

// ---------------------------------------------------------------------------
// ASA (AdaAttN-style) fused pipeline for MI355X / gfx950
// B=4, C=256, H=W=64 -> N=M=4096 tokens.
//
// R20 (prefix overhaul; k_flash = R19 verbatim, session best 291 us):
//  * k_gemm: barrier-free streaming rewrite. W fragments read DIRECTLY from
//    global/L2 (128 KB/mode, L2-hot; same 16x64B coalescing as X loads) --
//    no LDS, no per-ks barriers (16 deleted). 64-token tiles, grid
//    (64,4,3)=768 blocks = 3/CU. One __syncthreads before the epilogue
//    (mode-1 in-place hazard). Bit-identical outputs.
//  * k_stats fused into k_prep as z=15..18 (one fewer launch, overlapped).
//  * k_flash: R19 unchanged -- KVBLK=128, 512-thread block, K dbuf 128 KiB,
//    two 32-m phases/iter, m-split + flash-combine, T12/T13/T5.
//
//  ws layout unchanged (cm, cr, Wb, A=Qt, Bv=Vt, Cc=Kt; X1/X2 in d_out).
// ---------------------------------------------------------------------------

typedef unsigned int u32;
typedef unsigned short u16;
typedef _Float16 f16x8 __attribute__((ext_vector_type(8)));
typedef float f32x4 __attribute__((ext_vector_type(4)));
typedef float f32x16 __attribute__((ext_vector_type(16)));
typedef unsigned int u32x2 __attribute__((ext_vector_type(2)));
typedef unsigned __attribute__((address_space(3))) as3_u32;
typedef const unsigned __attribute__((address_space(1))) as1_u32;

#define L2E 1.44269504088896340736f
#define MFMA(a, b, c) __builtin_amdgcn_mfma_f32_16x16x32_f16(a, b, c, 0, 0, 0)
#define MFMA32(a, b, c) __builtin_amdgcn_mfma_f32_32x32x16_f16(a, b, c, 0, 0, 0)
#define EXP2(x) __builtin_amdgcn_exp2f(x)

__device__ __forceinline__ u16 h_bits(_Float16 h) { return __builtin_bit_cast(u16, h); }
__device__ __forceinline__ u16 f2h(float f) { return h_bits((_Float16)f); }
__device__ __forceinline__ u32 pk2(float a, float b) {
    return (u32)f2h(a) | ((u32)f2h(b) << 16);
}

__device__ __forceinline__ f16x8 ldh8(const u16* p) {
    uint4 v = *(const uint4*)p;
    return __builtin_bit_cast(f16x8, v);
}

// async 16B/lane global->LDS. lds must be wave-uniform; writes lds + lane*16.
__device__ __forceinline__ void gll16(const u16* g, const void* lds) {
    __builtin_amdgcn_global_load_lds((as1_u32*)g,
                                     (as3_u32*)(unsigned)(unsigned long long)lds,
                                     16, 0, 0);
}

// lane i<32: r.x = a[i],    r.y = a[i+32]
// lane i>=32: r.x = b[i-32], r.y = b[i]
__device__ __forceinline__ u32x2 pl32_swap(u32 a, u32 b) {
#if __has_builtin(__builtin_amdgcn_permlane32_swap)
    return __builtin_amdgcn_permlane32_swap(a, b, false, false);
#else
    asm("v_permlane32_swap_b32 %0, %1" : "+v"(a), "+v"(b));
    u32x2 r; r.x = a; r.y = b; return r;
#endif
}

// ---------------- prep: stats + 3 transposes + weight cvt, ONE launch -------
// z 0..3: style->X1 ; 4..7: ckey->X2 ; 8..11: skey->Cc ; 12..14: weights ;
// z 15..18: content stats (blk = (z-15)*256 + y*64 + x -> 0..1023)
__global__ void k_prep(const float* __restrict__ content,
                       const float* __restrict__ style, const float* __restrict__ ckey,
                       const float* __restrict__ skey,
                       const float* __restrict__ Wf, const float* __restrict__ Wg,
                       const float* __restrict__ Wh,
                       u16* __restrict__ X1, u16* __restrict__ X2, u16* __restrict__ Cc,
                       u16* __restrict__ Wb,
                       float* __restrict__ cm, float* __restrict__ cr) {
    int z = blockIdx.z, t = threadIdx.x;
    if (z >= 15) {
        // ---- content stats: mean & rstd per (b,c) ----
        int blk = (z - 15) * 256 + blockIdx.y * 64 + blockIdx.x;  // 0..1023
        const float* p = content + (size_t)blk * 4096;
        float s = 0.f, ss = 0.f;
        for (int i = 0; i < 4; i++) {
            float4 v = *(const float4*)(p + (i * 256 + t) * 4);
            s  += (v.x + v.y) + (v.z + v.w);
            ss += (v.x * v.x + v.y * v.y) + (v.z * v.z + v.w * v.w);
        }
        for (int d = 32; d >= 1; d >>= 1) { s += __shfl_xor(s, d); ss += __shfl_xor(ss, d); }
        __shared__ __align__(16) float as[4], ass[4];
        int w = t >> 6;
        if ((t & 63) == 0) { as[w] = s; ass[w] = ss; }
        __syncthreads();
        if (t == 0) {
            s  = (as[0] + as[1]) + (as[2] + as[3]);
            ss = (ass[0] + ass[1]) + (ass[2] + ass[3]);
            float mean = s * (1.0f / 4096.0f);
            float var = (ss - s * mean) * (1.0f / 4095.0f);   // unbiased (ddof=1)
            cm[blk] = mean;
            cr[blk] = rsqrtf(var + 1e-5f);
        }
        return;
    }
    if (z >= 12) {
        if (blockIdx.y != 0) return;
        int m = z - 12;
        const float* src = (m == 0) ? Wf : ((m == 1) ? Wg : Wh);
        u16* dst = Wb + m * 65536;
        int i = (blockIdx.x * 256 + t) * 4;
        float4 v = *(const float4*)(src + i);
        ushort4 o;
        o.x = f2h(v.x); o.y = f2h(v.y); o.z = f2h(v.z); o.w = f2h(v.w);
        *(ushort4*)(dst + i) = o;
        return;
    }
    int tensor = z >> 2, b = z & 3;
    const float* src = ((tensor == 0) ? style : ((tensor == 1) ? ckey : skey))
                       + (size_t)b * 256 * 4096;
    u16* dst = ((tensor == 0) ? X1 : ((tensor == 1) ? X2 : Cc)) + (size_t)b * 4096 * 256;
    int c0 = blockIdx.y * 64, t0 = blockIdx.x * 64;
    __shared__ __align__(16) float ls[64][65];
    int tr = t >> 4, tc = t & 15;
    for (int i = 0; i < 4; i++) {
        int c_off = i * 16 + tr;
        float4 v = *(const float4*)(src + (size_t)(c0 + c_off) * 4096 + t0 + tc * 4);
        ls[tc * 4 + 0][c_off] = v.x;
        ls[tc * 4 + 1][c_off] = v.y;
        ls[tc * 4 + 2][c_off] = v.z;
        ls[tc * 4 + 3][c_off] = v.w;
    }
    __syncthreads();
    for (int i = 0; i < 4; i++) {
        int tokrow = i * 16 + tr;
        ushort4 o;
        o.x = f2h(ls[tokrow][tc * 4 + 0]);
        o.y = f2h(ls[tokrow][tc * 4 + 1]);
        o.z = f2h(ls[tokrow][tc * 4 + 2]);
        o.w = f2h(ls[tokrow][tc * 4 + 3]);
        *(ushort4*)(dst + (size_t)(t0 + tokrow) * 256 + c0 + tc * 4) = o;
    }
}

// ---------------- all three conv1x1 GEMMs, barrier-free ---------------------
// mode 0: Q = X2*Wf^T + bf -> A (token-major)
// mode 1: K = Cc*Wg^T + bg -> Cc (in-place, token-major)
// mode 2: V = Wh*X1 + bh   -> Bv (channel-major)
// W fragments read directly from L2 (128 KB/mode); no LDS, no per-ks syncs.
__launch_bounds__(256)
__global__ void k_gemm(const u16* X1, const u16* X2, u16* Cc,
                       u16* A, u16* Bv, const u16* __restrict__ Wb,
                       const float* __restrict__ bfp, const float* __restrict__ bgp,
                       const float* __restrict__ bhp) {
    int mode = blockIdx.z, b = blockIdx.y, tok0 = blockIdx.x * 64;
    const u16* X = ((mode == 0) ? X2 : ((mode == 1) ? (const u16*)Cc : X1))
                   + (size_t)b * 4096 * 256;
    const u16* W = Wb + mode * 65536;
    const float* bias = (mode == 0) ? bfp : ((mode == 1) ? bgp : bhp);
    int t = threadIdx.x, w = t >> 6, lane = t & 63, ln = lane & 15, quad = lane >> 4;

    f32x4 acc[4][4];
    for (int i = 0; i < 4; i++)
        for (int j = 0; j < 4; j++) acc[i][j] = f32x4{0.f, 0.f, 0.f, 0.f};

    #pragma unroll
    for (int ks = 0; ks < 8; ks++) {
        f16x8 wf[4];
        #pragma unroll
        for (int ct = 0; ct < 4; ct++)
            wf[ct] = ldh8(W + (size_t)(w * 64 + ct * 16 + ln) * 256 + ks * 32 + quad * 8);
        #pragma unroll
        for (int rt = 0; rt < 4; rt++) {
            f16x8 xf = ldh8(X + (size_t)(tok0 + rt * 16 + ln) * 256 + ks * 32 + quad * 8);
            if (mode < 2) {
                #pragma unroll
                for (int ct = 0; ct < 4; ct++) acc[rt][ct] = MFMA(xf, wf[ct], acc[rt][ct]);
            } else {
                #pragma unroll
                for (int ct = 0; ct < 4; ct++) acc[rt][ct] = MFMA(wf[ct], xf, acc[rt][ct]);
            }
        }
    }

    // mode 1 writes in-place over its own X tile: ensure all reads done.
    __syncthreads();

    if (mode < 2) {
        u16* O = ((mode == 0) ? A : Cc) + (size_t)b * 4096 * 256;
        float bv[4];
        #pragma unroll
        for (int ct = 0; ct < 4; ct++) bv[ct] = bias[w * 64 + ct * 16 + ln];
        #pragma unroll
        for (int rt = 0; rt < 4; rt++)
            #pragma unroll
            for (int ct = 0; ct < 4; ct++)
                #pragma unroll
                for (int r = 0; r < 4; r++) {
                    int tok = tok0 + rt * 16 + quad * 4 + r;
                    int o = w * 64 + ct * 16 + ln;
                    O[(size_t)tok * 256 + o] = f2h(acc[rt][ct][r] + bv[ct]);
                }
    } else {
        u16* OV = Bv + (size_t)b * 256 * 4096;
        #pragma unroll
        for (int ct = 0; ct < 4; ct++)
            #pragma unroll
            for (int r = 0; r < 4; r++) {
                int o = w * 64 + ct * 16 + quad * 4 + r;
                float bb = bias[o];
                #pragma unroll
                for (int rt = 0; rt < 4; rt++) {
                    int tok = tok0 + rt * 16 + ln;
                    OV[(size_t)o * 4096 + tok] = f2h(acc[rt][ct][r] + bb);
                }
            }
    }
}

// ---------------- flash attention + fused AdaIN epilogue (R19) -------------
// grid: (32 q-tiles of 128, 4 batch, 2 c-halves) = 256 blocks = 1/CU.
// 8 waves = (qg 0..3) x (mh 0..1); wave: 32 q x 128 ch x its 64-m half,
// processed as two 32-m phases per iteration. 32 iterations, KVBLK=128.
// LDS: K[2][128][256] u16 swizzled (0, 65536B) = 128 KiB; epilogue reuses.
__launch_bounds__(512)
__attribute__((amdgpu_waves_per_eu(2)))
__global__ void k_flash(const u16* __restrict__ Qt, const u16* __restrict__ Kt,
                        const u16* __restrict__ Vt,
                        const float* __restrict__ content, const float* __restrict__ cm,
                        const float* __restrict__ cr, float* __restrict__ out) {
    __shared__ __align__(16) char smem[131072];
    const u16* KsU = (const u16*)smem;
    int t = threadIdx.x, w8 = t >> 6, l = t & 63, lq = l & 31, h = l >> 5;
    int qg = w8 & 3, mh = w8 >> 2;

    int b = blockIdx.y, q0 = blockIdx.x * 128, coff = blockIdx.z * 128;

    const u16* Kg = Kt + (size_t)b * 4096 * 256;
    const u16* Vg = Vt + ((size_t)b * 256 + coff) * 4096;

    // ---- K staging geometry (rule-21: linear LDS dest, inv-swizzled src) --
    const u16* ksrc;
    {
        int qb = w8 * 1024 + l * 16;                // 0..8191
        int r0 = qb >> 9;                           // 0..15
        int swz = (qb & 511) ^ ((r0 & 7) << 4);
        ksrc = Kg + r0 * 256 + (swz >> 1);          // + it*32768 + i*4096 (u16)
    }
    const char* ldsKw = smem + w8 * 1024;           // + koffB + i*8192

    // ---- K read-side swizzle: addr_u16 = row*256 + ((ks<<4) ^ uu) ----------
    int uu = (h ^ (lq & 7)) << 3;                   // u16 units
    int tab0 = uu, tab1 = 16 ^ uu, tab2 = 32 ^ uu, tab3 = 48 ^ uu;
    int kb0 = (mh * 64 + lq) * 256;                 // own m-half row base

    // Q as B-operand fragments, pinned: col q = lq, k = h*8+j (+16ks)
    f16x8 qf[16];
    {
        const u16* qp = Qt + ((size_t)b * 4096 + q0 + qg * 32 + lq) * 256 + h * 8;
        #pragma unroll
        for (int ks = 0; ks < 16; ks++) qf[ks] = ldh8(qp + ks * 16);
    }

    f32x16 am[4], aq[4];
    #pragma unroll
    for (int i = 0; i < 16; i++) {
        am[0][i] = 0.f; am[1][i] = 0.f; am[2][i] = 0.f; am[3][i] = 0.f;
        aq[0][i] = 0.f; aq[1][i] = 0.f; aq[2][i] = 0.f; aq[3][i] = 0.f;
    }
    float mrow = -1e30f, lrow = 0.f;                // per-wave (own 64-m half)

    // ---- prologue: stage K(0) into buffer 0 -------------------------------
    #pragma unroll
    for (int i = 0; i < 8; i++) gll16(ksrc + i * 4096, ldsKw + i * 8192);
    asm volatile("s_waitcnt vmcnt(0)" ::: "memory");
    __builtin_amdgcn_s_barrier();

    int koffB = 0;                                  // current K buffer (bytes)
    for (int it = 0; it < 32; it++) {
        // issue K(it+1) staging FIRST (coalesced; proven order) --
        // stays in flight until the end-of-iteration drain.
        if (it < 31) {
            int m0n = (it + 1) * 32768;             // (it+1)*128 rows * 256 u16
            #pragma unroll
            for (int i = 0; i < 8; i++)
                gll16(ksrc + m0n + i * 4096, ldsKw + (koffB ^ 65536) + i * 8192);
        }
        asm volatile("" ::: "memory");

        // ---- two 32-m phases over the staged 128-m tile (no barriers) ----
        #pragma unroll
        for (int ph = 0; ph < 2; ph++) {
            // S^T[m][q]: two independent 8-chains (MFMA ILP)
            int kb = (koffB >> 1) + kb0 + ph * 8192;
            f32x16 sA, sB;
            #pragma unroll
            for (int i = 0; i < 16; i++) { sA[i] = 0.f; sB[i] = 0.f; }
            __builtin_amdgcn_s_setprio(1);
            #pragma unroll
            for (int ks = 0; ks < 8; ks++) {
                int off = ((ks & 3) == 0 ? tab0 : (ks & 3) == 1 ? tab1
                          : (ks & 3) == 2 ? tab2 : tab3) + (ks >> 2) * 64;
                sA = MFMA32(ldh8(KsU + kb + off), qf[ks], sA);
            }
            #pragma unroll
            for (int ks = 8; ks < 16; ks++) {
                int off = ((ks & 3) == 0 ? tab0 : (ks & 3) == 1 ? tab1
                          : (ks & 3) == 2 ? tab2 : tab3) + (ks >> 2) * 64;
                sB = MFMA32(ldh8(KsU + kb + off), qf[ks], sB);
            }
            __builtin_amdgcn_s_setprio(0);
            f32x16 s;
            #pragma unroll
            for (int i = 0; i < 16; i++) s[i] = sA[i] + sB[i];

            // V fragments (own 32-m sub-tile) direct from global (L2);
            // issued after QK so their latency hides under the softmax.
            const u16* Vit = Vg + it * 128 + mh * 64 + ph * 32;
            f16x8 vfr[2][4];
            #pragma unroll
            for (int ks = 0; ks < 2; ks++)
                #pragma unroll
                for (int ct = 0; ct < 4; ct++)
                    vfr[ks][ct] = ldh8(Vit + (size_t)(ct * 32 + lq) * 4096 + ks * 16 + h * 8);

            // online softmax over 32 m: tree max + one shfl_xor(32)
            float m8[8];
            #pragma unroll
            for (int r = 0; r < 8; r++) m8[r] = fmaxf(s[r], s[r + 8]);
            #pragma unroll
            for (int d = 4; d >= 1; d >>= 1)
                #pragma unroll
                for (int r = 0; r < d; r++) m8[r] = fmaxf(m8[r], m8[r + d]);
            float mt = fmaxf(m8[0], __shfl_xor(m8[0], 32));

            // T13 defer-max: only rescale when some row grew by > 8 nats.
            float mn, al;
            bool resc = !__all(mt - mrow <= 8.0f);
            if (resc) {
                mn = fmaxf(mrow, mt);
                al = EXP2((mrow - mn) * L2E);
                mrow = mn;
            } else {
                mn = mrow;
                al = 1.0f;
            }
            float base = mn * L2E;
            #pragma unroll
            for (int r = 0; r < 16; r++)
                s[r] = (float)(_Float16)EXP2(__builtin_fmaf(s[r], L2E, -base));
            float a8[8];
            #pragma unroll
            for (int r = 0; r < 8; r++) a8[r] = s[r] + s[r + 8];
            #pragma unroll
            for (int d = 4; d >= 1; d >>= 1)
                #pragma unroll
                for (int r = 0; r < d; r++) a8[r] += a8[r + d];
            float rs = a8[0] + __shfl_xor(a8[0], 32);
            lrow = lrow * al + rs;

            if (resc) {
                #pragma unroll
                for (int r = 0; r < 16; r++) {
                    float sc = __shfl(al, 8 * (r >> 2) + 4 * h + (r & 3));
                    am[0][r] *= sc; am[1][r] *= sc; am[2][r] *= sc; am[3][r] *= sc;
                    aq[0][r] *= sc; aq[1][r] *= sc; aq[2][r] *= sc; aq[3][r] *= sc;
                }
            }

            // ---- T12: PV A-fragments in-register (single 32x32 tile) ----
            f16x8 pfr[2];
            {
                u32 d0 = pk2(s[0], s[1]),   d1 = pk2(s[2], s[3]);
                u32 d2 = pk2(s[4], s[5]),   d3 = pk2(s[6], s[7]);
                u32 d4 = pk2(s[8], s[9]),   d5 = pk2(s[10], s[11]);
                u32 d6 = pk2(s[12], s[13]), d7 = pk2(s[14], s[15]);
                u32x2 p02 = pl32_swap(d0, d2);
                u32x2 p13 = pl32_swap(d1, d3);
                u32x2 p46 = pl32_swap(d4, d6);
                u32x2 p57 = pl32_swap(d5, d7);
                uint4 fa = {p02.x, p13.x, p02.y, p13.y};
                uint4 fb = {p46.x, p57.x, p46.y, p57.y};
                pfr[0] = __builtin_bit_cast(f16x8, fa);
                pfr[1] = __builtin_bit_cast(f16x8, fb);
            }

            // PV: am[ct] += P*V ; aq[ct] += P*v2hi + P*v2lo (exact Dekker)
            __builtin_amdgcn_s_setprio(1);
            #pragma unroll
            for (int ks = 0; ks < 2; ks++) {
                f16x8 pf = pfr[ks];
                #pragma unroll
                for (int ct = 0; ct < 4; ct++) {
                    f16x8 vf = vfr[ks][ct];
                    am[ct] = MFMA32(pf, vf, am[ct]);
                    f16x8 vh = vf * vf;
                    f16x8 vl = __builtin_elementwise_fma(vf, vf, -vh);
                    aq[ct] = MFMA32(pf, vh, aq[ct]);
                    aq[ct] = MFMA32(pf, vl, aq[ct]);
                }
            }
            __builtin_amdgcn_s_setprio(0);
        }

        // drain K(it+1) writes (issued a full iteration ago) + sync; swap
        asm volatile("s_waitcnt vmcnt(0)" ::: "memory");
        __builtin_amdgcn_s_barrier();
        koffB ^= 65536;
    }

    // ------------- epilogue: merge m-halves, then AdaIN ---------------------
    // LDS: P1 @0 (32 KiB: am 0..4095, aq 4096..8191 floats) | Lsm @32768 |
    //      Ms @36864 (33792 B) | Ss @70656 (33792 B)
    float* P1  = (float*)smem;
    float* Lsm = (float*)(smem + 32768);
    float* Ms  = (float*)(smem + 36864);       // [64 c][132 q] f32
    float* Ss  = (float*)(smem + 70656);
    __syncthreads();
    if (h == 0) {
        Lsm[w8 * 32 + lq] = lrow;
        Lsm[256 + w8 * 32 + lq] = mrow;
    }
    __syncthreads();
    int pw = w8 ^ 4;                           // partner wave (other mh)
    float lP = Lsm[pw * 32 + lq];
    float mP = Lsm[256 + pw * 32 + lq];
    float M = fmaxf(mrow, mP);
    float scOwn = EXP2((mrow - M) * L2E);
    float lC = lrow * scOwn + lP * EXP2((mP - M) * L2E);
    {   // scale own partials to the common max
        #pragma unroll
        for (int r = 0; r < 16; r++) {
            float sc = __shfl(scOwn, 8 * (r >> 2) + 4 * h + (r & 3));
            am[0][r] *= sc; am[1][r] *= sc; am[2][r] *= sc; am[3][r] *= sc;
            aq[0][r] *= sc; aq[1][r] *= sc; aq[2][r] *= sc; aq[3][r] *= sc;
        }
    }
    float inv = 1.0f / lC;
    float iv[16];
    #pragma unroll
    for (int r = 0; r < 16; r++) iv[r] = __shfl(inv, (r & 3) + 8 * (r >> 2) + 4 * h);

    #pragma unroll
    for (int g = 0; g < 2; g++) {
        // combine per ct-chunk: mh=1 writes, mh=0 adds. [qg][c32][q32] f32 x2.
        #pragma unroll
        for (int ct = 0; ct < 2; ct++) {
            int a = 2 * g + ct;
            __syncthreads();
            if (mh == 1) {
                #pragma unroll
                for (int rq = 0; rq < 4; rq++) {
                    int o = qg * 1024 + lq * 32 + 8 * rq + 4 * h;
                    f32x4 va = {am[a][4 * rq], am[a][4 * rq + 1],
                                am[a][4 * rq + 2], am[a][4 * rq + 3]};
                    f32x4 vq = {aq[a][4 * rq], aq[a][4 * rq + 1],
                                aq[a][4 * rq + 2], aq[a][4 * rq + 3]};
                    *(f32x4*)(P1 + o) = va;
                    *(f32x4*)(P1 + 4096 + o) = vq;
                }
            }
            __syncthreads();
            if (mh == 0) {
                #pragma unroll
                for (int rq = 0; rq < 4; rq++) {
                    int o = qg * 1024 + lq * 32 + 8 * rq + 4 * h;
                    f32x4 va = *(const f32x4*)(P1 + o);
                    f32x4 vq = *(const f32x4*)(P1 + 4096 + o);
                    #pragma unroll
                    for (int j = 0; j < 4; j++) {
                        am[a][4 * rq + j] += va[j];
                        aq[a][4 * rq + j] += vq[j];
                    }
                }
            }
        }
        __syncthreads();
        // mean/std -> Ms/Ss (combined state lives in mh==0 waves)
        if (mh == 0) {
            #pragma unroll
            for (int ct = 0; ct < 2; ct++) {
                int a = 2 * g + ct;
                #pragma unroll
                for (int rq = 0; rq < 4; rq++) {
                    f32x4 mv, sv;
                    #pragma unroll
                    for (int j = 0; j < 4; j++) {
                        int r = 4 * rq + j;
                        float mean = am[a][r] * iv[r];
                        float ex2 = aq[a][r] * iv[r];
                        float var = ex2 - mean * mean;
                        mv[j] = mean;
                        sv[j] = sqrtf(fmaxf(var, 0.f));
                    }
                    int c = ct * 32 + lq;
                    int qloc = qg * 32 + 8 * rq + 4 * h;
                    *(f32x4*)(Ms + c * 132 + qloc) = mv;
                    *(f32x4*)(Ss + c * 132 + qloc) = sv;
                }
            }
        }
        __syncthreads();
        #pragma unroll
        for (int pass = 0; pass < 4; pass++) {
            int c = pass * 16 + (t >> 5);          // 0..63 within this g
            int qloc = (t & 31) * 4;               // 0..124
            f32x4 mv = *(const f32x4*)(Ms + c * 132 + qloc);
            f32x4 sv = *(const f32x4*)(Ss + c * 132 + qloc);
            int gc = coff + g * 64 + c;
            size_t basei = ((size_t)b * 256 + gc) * 4096 + q0 + qloc;
            float4 cv = *(const float4*)(content + basei);
            float cmv = cm[b * 256 + gc], crv = cr[b * 256 + gc];
            float4 o;
            o.x = sv[0] * ((cv.x - cmv) * crv) + mv[0];
            o.y = sv[1] * ((cv.y - cmv) * crv) + mv[1];
            o.z = sv[2] * ((cv.z - cmv) * crv) + mv[2];
            o.w = sv[3] * ((cv.w - cmv) * crv) + mv[3];
            *(float4*)(out + basei) = o;
        }
    }
}

// ---------------------------------------------------------------------------
extern "C" void kernel_launch(void* const* d_in, const int* in_sizes, int n_in,
                              void* d_out, int out_size, void* d_ws, size_t ws_size,
                              hipStream_t stream) {
    const float* content = (const float*)d_in[0];
    const float* style   = (const float*)d_in[1];
    const float* ckey    = (const float*)d_in[2];
    const float* skey    = (const float*)d_in[3];
    const float* Wf      = (const float*)d_in[4];
    const float* bfp     = (const float*)d_in[5];
    const float* Wg      = (const float*)d_in[6];
    const float* bgp     = (const float*)d_in[7];
    const float* Wh      = (const float*)d_in[8];
    const float* bhp     = (const float*)d_in[9];
    float* out = (float*)d_out;
    char* ws = (char*)d_ws;

    float* cm = (float*)(ws + 0);               //  4 KiB
    float* cr = (float*)(ws + 4096);            //  4 KiB
    u16*   Wb = (u16*)(ws + 8192);              //  384 KiB
    u16*   A  = (u16*)(ws + 1048576);           //  8 MiB: Qt
    u16*   Bv = (u16*)(ws + 9437184);           //  8 MiB: Vt [c][tok]
    u16*   Cc = (u16*)(ws + 17825792);          //  8 MiB: Xk -> Kt
    u16*   X1 = (u16*)d_out;                    //  8 MiB scratch (style^T)
    u16*   X2 = (u16*)d_out + 4194304;          //  8 MiB scratch (ckey^T)

    k_prep<<<dim3(64, 4, 19), 256, 0, stream>>>(content, style, ckey, skey,
                                                Wf, Wg, Wh, X1, X2, Cc, Wb, cm, cr);
    k_gemm<<<dim3(64, 4, 3), 256, 0, stream>>>(X1, X2, Cc, A, Bv, Wb, bfp, bgp, bhp);
    k_flash<<<dim3(32, 4, 2), 512, 0, stream>>>(A, Cc, Bv, content, cm, cr, out);
}

// Round 12
// 339.299 us; speedup vs baseline: 1.1955x; 1.1955x over previous
//
#include <hip/hip_runtime.h>

// ---------------------------------------------------------------------------
// ASA (AdaAttN-style) fused pipeline for MI355X / gfx950
// B=4, C=256, H=W=64 -> N=M=4096 tokens.
//
// R21 (= R20 + V staged through LDS; kills the V L2-gather storm):
//  * Diagnosis: V fragments read as 64-lane gathers at 8-KB stride pulled
//    ~512 KB/block-iter across L2->CU (~32 128-B lines per ldh8) -- ~9k
//    cycles of the invariant ~10k-cycle/iter hole across R9-R19.
//  * Fix: stage V(it) [128c][128m] (32 KB) into LDS via 4 coalesced
//    gll16/wave with 16-slot XOR swizzle (store slot l&15 from source col
//    (l&15)^(row&15); read slot col16^(lq&15) -- rule-21 involution).
//    LDS = 2x64K (K dbuf) + 32K (V) = 160 KiB exactly.
//  * Schedule: top issues V(it) (vmcnt ops 1-4) then K(it+1) (5-12,
//    wraparound so counts constant); before PV(ph0): vmcnt(8)+barrier
//    (drains V only; K prefetch stays in flight); end vmcnt(0)+barrier.
//  * Everything else R20-verbatim (prefix kernels, epilogue, T12/T13/T5).
//
//  ws layout unchanged (cm, cr, Wb, A=Qt, Bv=Vt, Cc=Kt; X1/X2 in d_out).
// ---------------------------------------------------------------------------

typedef unsigned int u32;
typedef unsigned short u16;
typedef _Float16 f16x8 __attribute__((ext_vector_type(8)));
typedef float f32x4 __attribute__((ext_vector_type(4)));
typedef float f32x16 __attribute__((ext_vector_type(16)));
typedef unsigned int u32x2 __attribute__((ext_vector_type(2)));
typedef unsigned __attribute__((address_space(3))) as3_u32;
typedef const unsigned __attribute__((address_space(1))) as1_u32;

#define L2E 1.44269504088896340736f
#define MFMA(a, b, c) __builtin_amdgcn_mfma_f32_16x16x32_f16(a, b, c, 0, 0, 0)
#define MFMA32(a, b, c) __builtin_amdgcn_mfma_f32_32x32x16_f16(a, b, c, 0, 0, 0)
#define EXP2(x) __builtin_amdgcn_exp2f(x)

__device__ __forceinline__ u16 h_bits(_Float16 h) { return __builtin_bit_cast(u16, h); }
__device__ __forceinline__ u16 f2h(float f) { return h_bits((_Float16)f); }
__device__ __forceinline__ u32 pk2(float a, float b) {
    return (u32)f2h(a) | ((u32)f2h(b) << 16);
}

__device__ __forceinline__ f16x8 ldh8(const u16* p) {
    uint4 v = *(const uint4*)p;
    return __builtin_bit_cast(f16x8, v);
}

// async 16B/lane global->LDS. lds must be wave-uniform; writes lds + lane*16.
__device__ __forceinline__ void gll16(const u16* g, const void* lds) {
    __builtin_amdgcn_global_load_lds((as1_u32*)g,
                                     (as3_u32*)(unsigned)(unsigned long long)lds,
                                     16, 0, 0);
}

// lane i<32: r.x = a[i],    r.y = a[i+32]
// lane i>=32: r.x = b[i-32], r.y = b[i]
__device__ __forceinline__ u32x2 pl32_swap(u32 a, u32 b) {
#if __has_builtin(__builtin_amdgcn_permlane32_swap)
    return __builtin_amdgcn_permlane32_swap(a, b, false, false);
#else
    asm("v_permlane32_swap_b32 %0, %1" : "+v"(a), "+v"(b));
    u32x2 r; r.x = a; r.y = b; return r;
#endif
}

// ---------------- prep: stats + 3 transposes + weight cvt, ONE launch -------
// z 0..3: style->X1 ; 4..7: ckey->X2 ; 8..11: skey->Cc ; 12..14: weights ;
// z 15..18: content stats (blk = (z-15)*256 + y*64 + x -> 0..1023)
__global__ void k_prep(const float* __restrict__ content,
                       const float* __restrict__ style, const float* __restrict__ ckey,
                       const float* __restrict__ skey,
                       const float* __restrict__ Wf, const float* __restrict__ Wg,
                       const float* __restrict__ Wh,
                       u16* __restrict__ X1, u16* __restrict__ X2, u16* __restrict__ Cc,
                       u16* __restrict__ Wb,
                       float* __restrict__ cm, float* __restrict__ cr) {
    int z = blockIdx.z, t = threadIdx.x;
    if (z >= 15) {
        // ---- content stats: mean & rstd per (b,c) ----
        int blk = (z - 15) * 256 + blockIdx.y * 64 + blockIdx.x;  // 0..1023
        const float* p = content + (size_t)blk * 4096;
        float s = 0.f, ss = 0.f;
        for (int i = 0; i < 4; i++) {
            float4 v = *(const float4*)(p + (i * 256 + t) * 4);
            s  += (v.x + v.y) + (v.z + v.w);
            ss += (v.x * v.x + v.y * v.y) + (v.z * v.z + v.w * v.w);
        }
        for (int d = 32; d >= 1; d >>= 1) { s += __shfl_xor(s, d); ss += __shfl_xor(ss, d); }
        __shared__ __align__(16) float as[4], ass[4];
        int w = t >> 6;
        if ((t & 63) == 0) { as[w] = s; ass[w] = ss; }
        __syncthreads();
        if (t == 0) {
            s  = (as[0] + as[1]) + (as[2] + as[3]);
            ss = (ass[0] + ass[1]) + (ass[2] + ass[3]);
            float mean = s * (1.0f / 4096.0f);
            float var = (ss - s * mean) * (1.0f / 4095.0f);   // unbiased (ddof=1)
            cm[blk] = mean;
            cr[blk] = rsqrtf(var + 1e-5f);
        }
        return;
    }
    if (z >= 12) {
        if (blockIdx.y != 0) return;
        int m = z - 12;
        const float* src = (m == 0) ? Wf : ((m == 1) ? Wg : Wh);
        u16* dst = Wb + m * 65536;
        int i = (blockIdx.x * 256 + t) * 4;
        float4 v = *(const float4*)(src + i);
        ushort4 o;
        o.x = f2h(v.x); o.y = f2h(v.y); o.z = f2h(v.z); o.w = f2h(v.w);
        *(ushort4*)(dst + i) = o;
        return;
    }
    int tensor = z >> 2, b = z & 3;
    const float* src = ((tensor == 0) ? style : ((tensor == 1) ? ckey : skey))
                       + (size_t)b * 256 * 4096;
    u16* dst = ((tensor == 0) ? X1 : ((tensor == 1) ? X2 : Cc)) + (size_t)b * 4096 * 256;
    int c0 = blockIdx.y * 64, t0 = blockIdx.x * 64;
    __shared__ __align__(16) float ls[64][65];
    int tr = t >> 4, tc = t & 15;
    for (int i = 0; i < 4; i++) {
        int c_off = i * 16 + tr;
        float4 v = *(const float4*)(src + (size_t)(c0 + c_off) * 4096 + t0 + tc * 4);
        ls[tc * 4 + 0][c_off] = v.x;
        ls[tc * 4 + 1][c_off] = v.y;
        ls[tc * 4 + 2][c_off] = v.z;
        ls[tc * 4 + 3][c_off] = v.w;
    }
    __syncthreads();
    for (int i = 0; i < 4; i++) {
        int tokrow = i * 16 + tr;
        ushort4 o;
        o.x = f2h(ls[tokrow][tc * 4 + 0]);
        o.y = f2h(ls[tokrow][tc * 4 + 1]);
        o.z = f2h(ls[tokrow][tc * 4 + 2]);
        o.w = f2h(ls[tokrow][tc * 4 + 3]);
        *(ushort4*)(dst + (size_t)(t0 + tokrow) * 256 + c0 + tc * 4) = o;
    }
}

// ---------------- all three conv1x1 GEMMs, barrier-free ---------------------
// mode 0: Q = X2*Wf^T + bf -> A (token-major)
// mode 1: K = Cc*Wg^T + bg -> Cc (in-place, token-major)
// mode 2: V = Wh*X1 + bh   -> Bv (channel-major)
// W fragments read directly from L2 (128 KB/mode); no LDS, no per-ks syncs.
__launch_bounds__(256)
__global__ void k_gemm(const u16* X1, const u16* X2, u16* Cc,
                       u16* A, u16* Bv, const u16* __restrict__ Wb,
                       const float* __restrict__ bfp, const float* __restrict__ bgp,
                       const float* __restrict__ bhp) {
    int mode = blockIdx.z, b = blockIdx.y, tok0 = blockIdx.x * 64;
    const u16* X = ((mode == 0) ? X2 : ((mode == 1) ? (const u16*)Cc : X1))
                   + (size_t)b * 4096 * 256;
    const u16* W = Wb + mode * 65536;
    const float* bias = (mode == 0) ? bfp : ((mode == 1) ? bgp : bhp);
    int t = threadIdx.x, w = t >> 6, lane = t & 63, ln = lane & 15, quad = lane >> 4;

    f32x4 acc[4][4];
    for (int i = 0; i < 4; i++)
        for (int j = 0; j < 4; j++) acc[i][j] = f32x4{0.f, 0.f, 0.f, 0.f};

    #pragma unroll
    for (int ks = 0; ks < 8; ks++) {
        f16x8 wf[4];
        #pragma unroll
        for (int ct = 0; ct < 4; ct++)
            wf[ct] = ldh8(W + (size_t)(w * 64 + ct * 16 + ln) * 256 + ks * 32 + quad * 8);
        #pragma unroll
        for (int rt = 0; rt < 4; rt++) {
            f16x8 xf = ldh8(X + (size_t)(tok0 + rt * 16 + ln) * 256 + ks * 32 + quad * 8);
            if (mode < 2) {
                #pragma unroll
                for (int ct = 0; ct < 4; ct++) acc[rt][ct] = MFMA(xf, wf[ct], acc[rt][ct]);
            } else {
                #pragma unroll
                for (int ct = 0; ct < 4; ct++) acc[rt][ct] = MFMA(wf[ct], xf, acc[rt][ct]);
            }
        }
    }

    // mode 1 writes in-place over its own X tile: ensure all reads done.
    __syncthreads();

    if (mode < 2) {
        u16* O = ((mode == 0) ? A : Cc) + (size_t)b * 4096 * 256;
        float bv[4];
        #pragma unroll
        for (int ct = 0; ct < 4; ct++) bv[ct] = bias[w * 64 + ct * 16 + ln];
        #pragma unroll
        for (int rt = 0; rt < 4; rt++)
            #pragma unroll
            for (int ct = 0; ct < 4; ct++)
                #pragma unroll
                for (int r = 0; r < 4; r++) {
                    int tok = tok0 + rt * 16 + quad * 4 + r;
                    int o = w * 64 + ct * 16 + ln;
                    O[(size_t)tok * 256 + o] = f2h(acc[rt][ct][r] + bv[ct]);
                }
    } else {
        u16* OV = Bv + (size_t)b * 256 * 4096;
        #pragma unroll
        for (int ct = 0; ct < 4; ct++)
            #pragma unroll
            for (int r = 0; r < 4; r++) {
                int o = w * 64 + ct * 16 + quad * 4 + r;
                float bb = bias[o];
                #pragma unroll
                for (int rt = 0; rt < 4; rt++) {
                    int tok = tok0 + rt * 16 + ln;
                    OV[(size_t)o * 4096 + tok] = f2h(acc[rt][ct][r] + bb);
                }
            }
    }
}

// ---------------- flash attention + fused AdaIN epilogue -------------------
// grid: (32 q-tiles of 128, 4 batch, 2 c-halves) = 256 blocks = 1/CU.
// 8 waves = (qg 0..3) x (mh 0..1); wave: 32 q x 128 ch x its 64-m half,
// processed as two 32-m phases per iteration. 32 iterations, KVBLK=128.
// LDS: K[2][128][256] u16 swz (0, 65536) | V[128][128] u16 swz (@131072)
//      = 160 KiB exactly. Epilogue reuses [0, 104448).
__launch_bounds__(512)
__attribute__((amdgpu_waves_per_eu(2)))
__global__ void k_flash(const u16* __restrict__ Qt, const u16* __restrict__ Kt,
                        const u16* __restrict__ Vt,
                        const float* __restrict__ content, const float* __restrict__ cm,
                        const float* __restrict__ cr, float* __restrict__ out) {
    __shared__ __align__(16) char smem[163840];
    const u16* KsU = (const u16*)smem;
    int t = threadIdx.x, w8 = t >> 6, l = t & 63, lq = l & 31, h = l >> 5;
    int qg = w8 & 3, mh = w8 >> 2;

    int b = blockIdx.y, q0 = blockIdx.x * 128, coff = blockIdx.z * 128;

    const u16* Kg = Kt + (size_t)b * 4096 * 256;
    const u16* Vg = Vt + ((size_t)b * 256 + coff) * 4096;

    // ---- K staging geometry (rule-21: linear LDS dest, inv-swizzled src) --
    const u16* ksrc;
    {
        int qb = w8 * 1024 + l * 16;                // 0..8191
        int r0 = qb >> 9;                           // 0..15
        int swz = (qb & 511) ^ ((r0 & 7) << 4);
        ksrc = Kg + r0 * 256 + (swz >> 1);          // + it*32768 + i*4096 (u16)
    }
    const char* ldsKw = smem + w8 * 1024;           // + koffB + i*8192

    // ---- V staging geometry: tile [128 c][128 m] u16, row = 256 B.
    // gll16 j = w8*4+i covers rows [4j, 4j+4); lane l -> row 4j+(l>>4),
    // slot col16 = l&15, SOURCE col16' = (l&15) ^ (row&15)  (involution).
    const char* ldsVw = smem + 131072 + w8 * 4096;  // + i*1024
    int vrow0 = w8 * 16 + (l >> 4);
    int vs0, vs1, vs2, vs3;                          // per-lane src offs (u16)
    {
        int r0v = vrow0,     k0v = ((l & 15) ^ (r0v & 15)) << 3;
        int r1v = vrow0 + 4, k1v = ((l & 15) ^ (r1v & 15)) << 3;
        int r2v = vrow0 + 8, k2v = ((l & 15) ^ (r2v & 15)) << 3;
        int r3v = vrow0 + 12, k3v = ((l & 15) ^ (r3v & 15)) << 3;
        vs0 = r0v * 4096 + k0v; vs1 = r1v * 4096 + k1v;
        vs2 = r2v * 4096 + k2v; vs3 = r3v * 4096 + k3v;
    }
    // V read side: row = ct*32+lq (u16 off ct*4096 + lq*128), logical col16 =
    // (mh<<3)|(ph<<2)|(ks<<1)|h, slot = col16 ^ (lq&15).
    int vb16 = 65536 + lq * 128;                     // u16 units (+ct*4096)
    int vcb  = ((mh << 3) | h) ^ (lq & 15);          // per-lane col base

    // ---- K read-side swizzle: addr_u16 = row*256 + ((ks<<4) ^ uu) ----------
    int uu = (h ^ (lq & 7)) << 3;                   // u16 units
    int tab0 = uu, tab1 = 16 ^ uu, tab2 = 32 ^ uu, tab3 = 48 ^ uu;
    int kb0 = (mh * 64 + lq) * 256;                 // own m-half row base

    // Q as B-operand fragments, pinned: col q = lq, k = h*8+j (+16ks)
    f16x8 qf[16];
    {
        const u16* qp = Qt + ((size_t)b * 4096 + q0 + qg * 32 + lq) * 256 + h * 8;
        #pragma unroll
        for (int ks = 0; ks < 16; ks++) qf[ks] = ldh8(qp + ks * 16);
    }

    f32x16 am[4], aq[4];
    #pragma unroll
    for (int i = 0; i < 16; i++) {
        am[0][i] = 0.f; am[1][i] = 0.f; am[2][i] = 0.f; am[3][i] = 0.f;
        aq[0][i] = 0.f; aq[1][i] = 0.f; aq[2][i] = 0.f; aq[3][i] = 0.f;
    }
    float mrow = -1e30f, lrow = 0.f;                // per-wave (own 64-m half)

    // ---- prologue: stage K(0) into buffer 0 -------------------------------
    #pragma unroll
    for (int i = 0; i < 8; i++) gll16(ksrc + i * 4096, ldsKw + i * 8192);
    asm volatile("s_waitcnt vmcnt(0)" ::: "memory");
    __builtin_amdgcn_s_barrier();

    int koffB = 0;                                  // current K buffer (bytes)
    for (int it = 0; it < 32; it++) {
        // V(it) staging FIRST (vmcnt ops 1-4): coalesced, swizzled source.
        {
            int m0v = it * 128;
            gll16(Vg + vs0 + m0v, ldsVw + 0);
            gll16(Vg + vs1 + m0v, ldsVw + 1024);
            gll16(Vg + vs2 + m0v, ldsVw + 2048);
            gll16(Vg + vs3 + m0v, ldsVw + 3072);
        }
        asm volatile("" ::: "memory");
        // K(it+1) staging (ops 5-12; wraparound keeps counts constant) --
        // stays in flight until the end-of-iteration drain.
        {
            int m0n = ((it + 1) & 31) * 32768;      // rows * 256 u16
            #pragma unroll
            for (int i = 0; i < 8; i++)
                gll16(ksrc + m0n + i * 4096, ldsKw + (koffB ^ 65536) + i * 8192);
        }
        asm volatile("" ::: "memory");

        // ---- two 32-m phases over the staged 128-m tile ----
        #pragma unroll
        for (int ph = 0; ph < 2; ph++) {
            // S^T[m][q]: two independent 8-chains (MFMA ILP)
            int kb = (koffB >> 1) + kb0 + ph * 8192;
            f32x16 sA, sB;
            #pragma unroll
            for (int i = 0; i < 16; i++) { sA[i] = 0.f; sB[i] = 0.f; }
            __builtin_amdgcn_s_setprio(1);
            #pragma unroll
            for (int ks = 0; ks < 8; ks++) {
                int off = ((ks & 3) == 0 ? tab0 : (ks & 3) == 1 ? tab1
                          : (ks & 3) == 2 ? tab2 : tab3) + (ks >> 2) * 64;
                sA = MFMA32(ldh8(KsU + kb + off), qf[ks], sA);
            }
            #pragma unroll
            for (int ks = 8; ks < 16; ks++) {
                int off = ((ks & 3) == 0 ? tab0 : (ks & 3) == 1 ? tab1
                          : (ks & 3) == 2 ? tab2 : tab3) + (ks >> 2) * 64;
                sB = MFMA32(ldh8(KsU + kb + off), qf[ks], sB);
            }
            __builtin_amdgcn_s_setprio(0);
            f32x16 s;
            #pragma unroll
            for (int i = 0; i < 16; i++) s[i] = sA[i] + sB[i];

            // online softmax over 32 m: tree max + one shfl_xor(32)
            float m8[8];
            #pragma unroll
            for (int r = 0; r < 8; r++) m8[r] = fmaxf(s[r], s[r + 8]);
            #pragma unroll
            for (int d = 4; d >= 1; d >>= 1)
                #pragma unroll
                for (int r = 0; r < d; r++) m8[r] = fmaxf(m8[r], m8[r + d]);
            float mt = fmaxf(m8[0], __shfl_xor(m8[0], 32));

            // T13 defer-max: only rescale when some row grew by > 8 nats.
            float mn, al;
            bool resc = !__all(mt - mrow <= 8.0f);
            if (resc) {
                mn = fmaxf(mrow, mt);
                al = EXP2((mrow - mn) * L2E);
                mrow = mn;
            } else {
                mn = mrow;
                al = 1.0f;
            }
            float base = mn * L2E;
            #pragma unroll
            for (int r = 0; r < 16; r++)
                s[r] = (float)(_Float16)EXP2(__builtin_fmaf(s[r], L2E, -base));
            float a8[8];
            #pragma unroll
            for (int r = 0; r < 8; r++) a8[r] = s[r] + s[r + 8];
            #pragma unroll
            for (int d = 4; d >= 1; d >>= 1)
                #pragma unroll
                for (int r = 0; r < d; r++) a8[r] += a8[r + d];
            float rs = a8[0] + __shfl_xor(a8[0], 32);
            lrow = lrow * al + rs;

            if (resc) {
                #pragma unroll
                for (int r = 0; r < 16; r++) {
                    float sc = __shfl(al, 8 * (r >> 2) + 4 * h + (r & 3));
                    am[0][r] *= sc; am[1][r] *= sc; am[2][r] *= sc; am[3][r] *= sc;
                    aq[0][r] *= sc; aq[1][r] *= sc; aq[2][r] *= sc; aq[3][r] *= sc;
                }
            }

            // ---- T12: PV A-fragments in-register (single 32x32 tile) ----
            f16x8 pfr[2];
            {
                u32 d0 = pk2(s[0], s[1]),   d1 = pk2(s[2], s[3]);
                u32 d2 = pk2(s[4], s[5]),   d3 = pk2(s[6], s[7]);
                u32 d4 = pk2(s[8], s[9]),   d5 = pk2(s[10], s[11]);
                u32 d6 = pk2(s[12], s[13]), d7 = pk2(s[14], s[15]);
                u32x2 p02 = pl32_swap(d0, d2);
                u32x2 p13 = pl32_swap(d1, d3);
                u32x2 p46 = pl32_swap(d4, d6);
                u32x2 p57 = pl32_swap(d5, d7);
                uint4 fa = {p02.x, p13.x, p02.y, p13.y};
                uint4 fb = {p46.x, p57.x, p46.y, p57.y};
                pfr[0] = __builtin_bit_cast(f16x8, fa);
                pfr[1] = __builtin_bit_cast(f16x8, fb);
            }

            // before first PV: V(it) landed (oldest 4 of 12); K stays in
            // flight. Barrier: all waves' V writes visible to all readers.
            if (ph == 0) {
                asm volatile("s_waitcnt vmcnt(8)" ::: "memory");
                __builtin_amdgcn_s_barrier();
                asm volatile("" ::: "memory");
            }

            // PV from V-LDS: am[ct] += P*V ; aq[ct] += P*v2hi + P*v2lo.
            __builtin_amdgcn_s_setprio(1);
            #pragma unroll
            for (int ks = 0; ks < 2; ks++) {
                f16x8 pf = pfr[ks];
                int col = (vcb ^ (ph << 2) ^ (ks << 1)) << 3;
                #pragma unroll
                for (int ct = 0; ct < 4; ct++) {
                    f16x8 vf = ldh8(KsU + vb16 + ct * 4096 +
                                    (((vcb ^ (ph << 2) ^ (ks << 1))) << 3));
                    (void)col;
                    am[ct] = MFMA32(pf, vf, am[ct]);
                    f16x8 vh = vf * vf;
                    f16x8 vl = __builtin_elementwise_fma(vf, vf, -vh);
                    aq[ct] = MFMA32(pf, vh, aq[ct]);
                    aq[ct] = MFMA32(pf, vl, aq[ct]);
                }
            }
            __builtin_amdgcn_s_setprio(0);
        }

        // drain K(it+1) writes (issued a full iteration ago) + sync; swap
        asm volatile("s_waitcnt vmcnt(0)" ::: "memory");
        __builtin_amdgcn_s_barrier();
        koffB ^= 65536;
    }

    // ------------- epilogue: merge m-halves, then AdaIN ---------------------
    // LDS: P1 @0 (32 KiB: am 0..4095, aq 4096..8191 floats) | Lsm @32768 |
    //      Ms @36864 (33792 B) | Ss @70656 (33792 B)
    float* P1  = (float*)smem;
    float* Lsm = (float*)(smem + 32768);
    float* Ms  = (float*)(smem + 36864);       // [64 c][132 q] f32
    float* Ss  = (float*)(smem + 70656);
    __syncthreads();
    if (h == 0) {
        Lsm[w8 * 32 + lq] = lrow;
        Lsm[256 + w8 * 32 + lq] = mrow;
    }
    __syncthreads();
    int pw = w8 ^ 4;                           // partner wave (other mh)
    float lP = Lsm[pw * 32 + lq];
    float mP = Lsm[256 + pw * 32 + lq];
    float M = fmaxf(mrow, mP);
    float scOwn = EXP2((mrow - M) * L2E);
    float lC = lrow * scOwn + lP * EXP2((mP - M) * L2E);
    {   // scale own partials to the common max
        #pragma unroll
        for (int r = 0; r < 16; r++) {
            float sc = __shfl(scOwn, 8 * (r >> 2) + 4 * h + (r & 3));
            am[0][r] *= sc; am[1][r] *= sc; am[2][r] *= sc; am[3][r] *= sc;
            aq[0][r] *= sc; aq[1][r] *= sc; aq[2][r] *= sc; aq[3][r] *= sc;
        }
    }
    float inv = 1.0f / lC;
    float iv[16];
    #pragma unroll
    for (int r = 0; r < 16; r++) iv[r] = __shfl(inv, (r & 3) + 8 * (r >> 2) + 4 * h);

    #pragma unroll
    for (int g = 0; g < 2; g++) {
        // combine per ct-chunk: mh=1 writes, mh=0 adds. [qg][c32][q32] f32 x2.
        #pragma unroll
        for (int ct = 0; ct < 2; ct++) {
            int a = 2 * g + ct;
            __syncthreads();
            if (mh == 1) {
                #pragma unroll
                for (int rq = 0; rq < 4; rq++) {
                    int o = qg * 1024 + lq * 32 + 8 * rq + 4 * h;
                    f32x4 va = {am[a][4 * rq], am[a][4 * rq + 1],
                                am[a][4 * rq + 2], am[a][4 * rq + 3]};
                    f32x4 vq = {aq[a][4 * rq], aq[a][4 * rq + 1],
                                aq[a][4 * rq + 2], aq[a][4 * rq + 3]};
                    *(f32x4*)(P1 + o) = va;
                    *(f32x4*)(P1 + 4096 + o) = vq;
                }
            }
            __syncthreads();
            if (mh == 0) {
                #pragma unroll
                for (int rq = 0; rq < 4; rq++) {
                    int o = qg * 1024 + lq * 32 + 8 * rq + 4 * h;
                    f32x4 va = *(const f32x4*)(P1 + o);
                    f32x4 vq = *(const f32x4*)(P1 + 4096 + o);
                    #pragma unroll
                    for (int j = 0; j < 4; j++) {
                        am[a][4 * rq + j] += va[j];
                        aq[a][4 * rq + j] += vq[j];
                    }
                }
            }
        }
        __syncthreads();
        // mean/std -> Ms/Ss (combined state lives in mh==0 waves)
        if (mh == 0) {
            #pragma unroll
            for (int ct = 0; ct < 2; ct++) {
                int a = 2 * g + ct;
                #pragma unroll
                for (int rq = 0; rq < 4; rq++) {
                    f32x4 mv, sv;
                    #pragma unroll
                    for (int j = 0; j < 4; j++) {
                        int r = 4 * rq + j;
                        float mean = am[a][r] * iv[r];
                        float ex2 = aq[a][r] * iv[r];
                        float var = ex2 - mean * mean;
                        mv[j] = mean;
                        sv[j] = sqrtf(fmaxf(var, 0.f));
                    }
                    int c = ct * 32 + lq;
                    int qloc = qg * 32 + 8 * rq + 4 * h;
                    *(f32x4*)(Ms + c * 132 + qloc) = mv;
                    *(f32x4*)(Ss + c * 132 + qloc) = sv;
                }
            }
        }
        __syncthreads();
        #pragma unroll
        for (int pass = 0; pass < 4; pass++) {
            int c = pass * 16 + (t >> 5);          // 0..63 within this g
            int qloc = (t & 31) * 4;               // 0..124
            f32x4 mv = *(const f32x4*)(Ms + c * 132 + qloc);
            f32x4 sv = *(const f32x4*)(Ss + c * 132 + qloc);
            int gc = coff + g * 64 + c;
            size_t basei = ((size_t)b * 256 + gc) * 4096 + q0 + qloc;
            float4 cv = *(const float4*)(content + basei);
            float cmv = cm[b * 256 + gc], crv = cr[b * 256 + gc];
            float4 o;
            o.x = sv[0] * ((cv.x - cmv) * crv) + mv[0];
            o.y = sv[1] * ((cv.y - cmv) * crv) + mv[1];
            o.z = sv[2] * ((cv.z - cmv) * crv) + mv[2];
            o.w = sv[3] * ((cv.w - cmv) * crv) + mv[3];
            *(float4*)(out + basei) = o;
        }
    }
}

// ---------------------------------------------------------------------------
extern "C" void kernel_launch(void* const* d_in, const int* in_sizes, int n_in,
                              void* d_out, int out_size, void* d_ws, size_t ws_size,
                              hipStream_t stream) {
    const float* content = (const float*)d_in[0];
    const float* style   = (const float*)d_in[1];
    const float* ckey    = (const float*)d_in[2];
    const float* skey    = (const float*)d_in[3];
    const float* Wf      = (const float*)d_in[4];
    const float* bfp     = (const float*)d_in[5];
    const float* Wg      = (const float*)d_in[6];
    const float* bgp     = (const float*)d_in[7];
    const float* Wh      = (const float*)d_in[8];
    const float* bhp     = (const float*)d_in[9];
    float* out = (float*)d_out;
    char* ws = (char*)d_ws;

    float* cm = (float*)(ws + 0);               //  4 KiB
    float* cr = (float*)(ws + 4096);            //  4 KiB
    u16*   Wb = (u16*)(ws + 8192);              //  384 KiB
    u16*   A  = (u16*)(ws + 1048576);           //  8 MiB: Qt
    u16*   Bv = (u16*)(ws + 9437184);           //  8 MiB: Vt [c][tok]
    u16*   Cc = (u16*)(ws + 17825792);          //  8 MiB: Xk -> Kt
    u16*   X1 = (u16*)d_out;                    //  8 MiB scratch (style^T)
    u16*   X2 = (u16*)d_out + 4194304;          //  8 MiB scratch (ckey^T)

    k_prep<<<dim3(64, 4, 19), 256, 0, stream>>>(content, style, ckey, skey,
                                                Wf, Wg, Wh, X1, X2, Cc, Wb, cm, cr);
    k_gemm<<<dim3(64, 4, 3), 256, 0, stream>>>(X1, X2, Cc, A, Bv, Wb, bfp, bgp, bhp);
    k_flash<<<dim3(32, 4, 2), 512, 0, stream>>>(A, Cc, Bv, content, cm, cr, out);
}